// Round 6
// baseline (418.069 us; speedup 1.0000x reference)
//
#include <hip/hip_runtime.h>
#include <stdint.h>

typedef unsigned int u32;
typedef unsigned short ushort_t;

#define T_ 4
#define B_ 16
#define C_ 256
#define N_ 1024
#define CN (C_ * N_)                 /* 262144 */
#define M_ELEMS (64 * C_ * N_)       /* 16777216 elems per [TB,C,N] tensor */

/* workspace byte offsets (ws >= ~138 MB) */
#define OFF_S    0ull                          /* SQ,SK,SV u8: 3*16.7MB */
#define OFF_XC   67108864ull                   /* Xc bf16 [64 tb][16 slab][1024 n][32 k] = 64MB; later aliased by Sc */
#define OFF_SC   67108864ull                   /* Sc bf16 [64 tb][8 kb][1024 n][32 k] = 32MB */
#define OFF_KV   134217728ull                  /* fp32 [64][8][32][32] = 2MB */
#define OFF_BNS  136314880ull                  /* float4 per channel-slot: 1024*16B = 16KB */
#define OFF_WC   136331264ull                  /* Wc bf16 [3][256][768] = 1.125MB */
#define OFF_WPC  137510912ull                  /* Wpc bf16 [256][512] = 256KB */

typedef __attribute__((ext_vector_type(8))) short bf16x8;
typedef __attribute__((ext_vector_type(4))) float f32x4;

/* XOR swizzle of 16B slots within a 64B LDS row (kept from R5; reads may become critical
   now that the stage drain is amortized). */
#define SWZ(c) (((c) & ~3) | (((c) & 3) ^ (((c) >> 2) & 3) ^ (((c) >> 4) & 3)))

#define WAITV(N) asm volatile("s_waitcnt vmcnt(" #N ")" ::: "memory")

__device__ __forceinline__ ushort_t f2bf(float f) {
  u32 u = __float_as_uint(f);
  u32 r = (u + 0x7FFFu + ((u >> 16) & 1u)) >> 16;
  return (ushort_t)r;
}
__device__ __forceinline__ float bf2f(ushort_t h) { return __uint_as_float((u32)h << 16); }

__device__ __forceinline__ void async_copy16(const void* g, void* l) {
  __builtin_amdgcn_global_load_lds(
      (const __attribute__((address_space(1))) u32*)g,
      (__attribute__((address_space(3))) u32*)l, 16, 0, 0);
}

/* 16-MFMA group: 4 a-frags from Ap against 4 preloaded b-frags, accumulate acc[0..15] */
__device__ __forceinline__ void mfma_grp(const ushort_t* Ap, int aoff,
                                         bf16x8 b0, bf16x8 b1, bf16x8 b2, bf16x8 b3,
                                         f32x4* acc) {
  bf16x8 a0 = *(const bf16x8*)&Ap[aoff + 0 * 16 * 32];
  bf16x8 a1 = *(const bf16x8*)&Ap[aoff + 1 * 16 * 32];
  bf16x8 a2 = *(const bf16x8*)&Ap[aoff + 2 * 16 * 32];
  bf16x8 a3 = *(const bf16x8*)&Ap[aoff + 3 * 16 * 32];
  acc[0]  = __builtin_amdgcn_mfma_f32_16x16x32_bf16(a0, b0, acc[0],  0, 0, 0);
  acc[1]  = __builtin_amdgcn_mfma_f32_16x16x32_bf16(a0, b1, acc[1],  0, 0, 0);
  acc[2]  = __builtin_amdgcn_mfma_f32_16x16x32_bf16(a0, b2, acc[2],  0, 0, 0);
  acc[3]  = __builtin_amdgcn_mfma_f32_16x16x32_bf16(a0, b3, acc[3],  0, 0, 0);
  acc[4]  = __builtin_amdgcn_mfma_f32_16x16x32_bf16(a1, b0, acc[4],  0, 0, 0);
  acc[5]  = __builtin_amdgcn_mfma_f32_16x16x32_bf16(a1, b1, acc[5],  0, 0, 0);
  acc[6]  = __builtin_amdgcn_mfma_f32_16x16x32_bf16(a1, b2, acc[6],  0, 0, 0);
  acc[7]  = __builtin_amdgcn_mfma_f32_16x16x32_bf16(a1, b3, acc[7],  0, 0, 0);
  acc[8]  = __builtin_amdgcn_mfma_f32_16x16x32_bf16(a2, b0, acc[8],  0, 0, 0);
  acc[9]  = __builtin_amdgcn_mfma_f32_16x16x32_bf16(a2, b1, acc[9],  0, 0, 0);
  acc[10] = __builtin_amdgcn_mfma_f32_16x16x32_bf16(a2, b2, acc[10], 0, 0, 0);
  acc[11] = __builtin_amdgcn_mfma_f32_16x16x32_bf16(a2, b3, acc[11], 0, 0, 0);
  acc[12] = __builtin_amdgcn_mfma_f32_16x16x32_bf16(a3, b0, acc[12], 0, 0, 0);
  acc[13] = __builtin_amdgcn_mfma_f32_16x16x32_bf16(a3, b1, acc[13], 0, 0, 0);
  acc[14] = __builtin_amdgcn_mfma_f32_16x16x32_bf16(a3, b2, acc[14], 0, 0, 0);
  acc[15] = __builtin_amdgcn_mfma_f32_16x16x32_bf16(a3, b3, acc[15], 0, 0, 0);
}

/* ---- BN coefficient prep: per channel-slot float4 {sc, shift, 1/sc, 0} ---- */
__global__ void bn_prep(const float* __restrict__ qg, const float* __restrict__ qb2, const float* __restrict__ qm, const float* __restrict__ qv,
                        const float* __restrict__ kg, const float* __restrict__ kb, const float* __restrict__ km, const float* __restrict__ kvv,
                        const float* __restrict__ vg, const float* __restrict__ vb, const float* __restrict__ vm, const float* __restrict__ vv,
                        const float* __restrict__ pbias,
                        const float* __restrict__ pg, const float* __restrict__ pbt, const float* __restrict__ pm, const float* __restrict__ pv,
                        float* __restrict__ bns) {
  int i = threadIdx.x;  /* 1024 threads */
  int br = i >> 8, c = i & 255;
  const float *g, *bt, *m, *v;
  float bias = 0.f;
  if (br == 0)      { g = qg; bt = qb2; m = qm; v = qv; }
  else if (br == 1) { g = kg; bt = kb;  m = km; v = kvv; }
  else if (br == 2) { g = vg; bt = vb;  m = vm; v = vv; }
  else              { g = pg; bt = pbt; m = pm; v = pv; bias = pbias[c]; }
  float sc = g[c] / sqrtf(v[c] + 1e-5f);
  float sh = bt[c] + (bias - m[c]) * sc;
  float rcp = (sc != 0.f) ? (1.f / sc) : 0.f;
  *(float4*)&bns[4 * i] = make_float4(sc, sh, rcp, 0.f);
}

/* ---- split weights to bf16 hi/lo. Wc[br][256][768] = [hi|lo|hi]; Wpc[256][512] = [hi|lo] ---- */
__global__ __launch_bounds__(256) void convert_w(const float* __restrict__ qw, const float* __restrict__ kw,
                                                 const float* __restrict__ vw, const float* __restrict__ pw,
                                                 ushort_t* __restrict__ Wc, ushort_t* __restrict__ Wpc) {
  int id = blockIdx.x * 256 + threadIdx.x;   /* 4*65536 */
  int br = id >> 16, o = (id >> 8) & 255, c = id & 255;
  const float* w = (br == 0) ? qw : (br == 1) ? kw : (br == 2) ? vw : pw;
  float f = w[o * 256 + c];
  ushort_t hi = f2bf(f);
  ushort_t lo = f2bf(f - bf2f(hi));
  if (br < 3) {
    ushort_t* d = Wc + (size_t)br * 196608 + (size_t)o * 768 + c;
    d[0] = hi; d[256] = lo; d[512] = hi;
  } else {
    ushort_t* d = Wpc + (size_t)o * 512 + c;
    d[0] = hi; d[256] = lo;
  }
}

/* ---- x fp32 [tb][256 c][1024 n] -> Xc bf16 [tb][16 slab][1024 n][32 k]; slab kb<8 = hi, 8+kb = lo ---- */
__global__ __launch_bounds__(256) void convert_x(const float* __restrict__ x, ushort_t* __restrict__ Xc) {
  __shared__ ushort_t hi[32][260];
  __shared__ ushort_t lo[32][260];
  int bid = blockIdx.x;
  int nc = bid & 3, kb = (bid >> 2) & 7, tb = bid >> 5;
  int t = threadIdx.x;
  int n0 = nc * 256;
  const float* xb = x + (size_t)tb * CN + (size_t)(kb * 32) * N_ + n0;
#pragma unroll
  for (int p = 0; p < 8; ++p) {
    int k = p * 4 + (t >> 6);
    int n4 = (t & 63) * 4;
    float4 v = *(const float4*)&xb[(size_t)k * N_ + n4];
    ushort_t h0 = f2bf(v.x), h1 = f2bf(v.y), h2 = f2bf(v.z), h3 = f2bf(v.w);
    short4 hv = make_short4((short)h0, (short)h1, (short)h2, (short)h3);
    short4 lv = make_short4((short)f2bf(v.x - bf2f(h0)), (short)f2bf(v.y - bf2f(h1)),
                            (short)f2bf(v.z - bf2f(h2)), (short)f2bf(v.w - bf2f(h3)));
    *(short4*)&hi[k][n4] = hv;
    *(short4*)&lo[k][n4] = lv;
  }
  __syncthreads();
  ushort_t* Hs = Xc + ((size_t)(tb * 16 + kb) * 1024 + n0) * 32;
  ushort_t* Ls = Xc + ((size_t)(tb * 16 + 8 + kb) * 1024 + n0) * 32;
  int kq = t & 3;
#pragma unroll
  for (int q = 0; q < 4; ++q) {
    int n = q * 64 + (t >> 2);
    u32 a0 = (u32)hi[kq * 8 + 0][n] | ((u32)hi[kq * 8 + 1][n] << 16);
    u32 a1 = (u32)hi[kq * 8 + 2][n] | ((u32)hi[kq * 8 + 3][n] << 16);
    u32 a2 = (u32)hi[kq * 8 + 4][n] | ((u32)hi[kq * 8 + 5][n] << 16);
    u32 a3 = (u32)hi[kq * 8 + 6][n] | ((u32)hi[kq * 8 + 7][n] << 16);
    *(uint4*)(Hs + (size_t)n * 32 + kq * 8) = make_uint4(a0, a1, a2, a3);
    u32 b0 = (u32)lo[kq * 8 + 0][n] | ((u32)lo[kq * 8 + 1][n] << 16);
    u32 b1 = (u32)lo[kq * 8 + 2][n] | ((u32)lo[kq * 8 + 3][n] << 16);
    u32 b2 = (u32)lo[kq * 8 + 4][n] | ((u32)lo[kq * 8 + 5][n] << 16);
    u32 b3 = (u32)lo[kq * 8 + 6][n] | ((u32)lo[kq * 8 + 7][n] << 16);
    *(uint4*)(Ls + (size_t)n * 32 + kq * 8) = make_uint4(b0, b1, b2, b3);
  }
}

/* ---- fused q/k/v MFMA GEMM (K'=768 bf16-split) + BN + LIF -> u8 spikes.
   grid (8 nt, 6 mt, 16 b); tile 128x128; membrane-in-accumulator across t.
   Pipelined: 96 chunks (BK=32, 16 MFMA each), 3 LDS buffers, prefetch distance 2,
   raw s_barrier + counted vmcnt(8) — loads stay in flight across barriers. ---- */
__global__ __launch_bounds__(256, 3) void gemm_qkv_lif(
    const ushort_t* __restrict__ Wc, const ushort_t* __restrict__ Xc,
    const float* __restrict__ bns, uint8_t* __restrict__ S) {
  __shared__ ushort_t L[3][8192];   /* 3 x 16KB: [A 128x32 | B 128x32] */
  const int nt = blockIdx.x, mt = blockIdx.y, b = blockIdx.z;
  const int br = mt >> 1, rh = mt & 1;
  const ushort_t* Ab = Wc + (size_t)br * 196608 + (size_t)(rh * 128) * 768;
  const int tid = threadIdx.x;
  const int lane = tid & 63;
  const int quad = lane >> 4, r = lane & 15;
  const int w = tid >> 6;
  const int moff = (w & 1) * 64, noff = (w >> 1) * 64;
  const int c0 = tid, c1 = tid + 256;       /* staging chunk ids (linear LDS dest) */
  const int s0 = SWZ(c0), s1 = SWZ(c1);     /* swizzled source slots */
  const int qx = quad ^ (r & 3) ^ ((r >> 2) & 3);  /* read-side slot XOR */
  const int aoff = (moff + r) * 32 + qx * 8;
  const int boff = 4096 + (noff + r) * 32 + qx * 8;

  auto STAGE = [&](int gS, int bi) {
    const int tS = gS / 24;
    const int jS = gS - tS * 24;
    const ushort_t* Acol = Ab + jS * 32;                      /* [hi|lo|hi] cols */
    const int slab = (jS < 8) ? jS : (jS - 8);                /* X slab: hi,hi,lo */
    const ushort_t* Bb = Xc + ((size_t)(tS * 16 + b) * 16 + slab) * 32768 +
                         (size_t)(nt * 128) * 32;
    ushort_t* Lb = &L[bi][0];
    async_copy16(Acol + (size_t)(c0 >> 2) * 768 + (s0 & 3) * 8, Lb + c0 * 8);
    async_copy16(Acol + (size_t)(c1 >> 2) * 768 + (s1 & 3) * 8, Lb + c1 * 8);
    async_copy16(Bb + s0 * 8, Lb + 4096 + c0 * 8);
    async_copy16(Bb + s1 * 8, Lb + 4096 + c1 * 8);
  };

  f32x4 acc[16];
#pragma unroll
  for (int f = 0; f < 16; ++f) acc[f] = (f32x4){0.f, 0.f, 0.f, 0.f};

  /* prologue: chunks 0,1 in flight */
  STAGE(0, 0);
  STAGE(1, 1);
  int cb = 0, sb = 2;

#pragma unroll 1
  for (int g = 0; g < 96; ++g) {
    __builtin_amdgcn_s_barrier();            /* A: target buffer's readers done */
    __builtin_amdgcn_sched_barrier(0);
    if (g < 94) STAGE(g + 2, sb);
    if (g < 94)      { WAITV(8); }           /* retire stage(g); 8 newer in flight */
    else if (g == 94){ WAITV(4); }
    else             { WAITV(0); }
    __builtin_amdgcn_s_barrier();            /* B: stage(g) visible to all waves */
    __builtin_amdgcn_sched_barrier(0);
    {
      const ushort_t* Lc = &L[cb][0];
      bf16x8 q0 = *(const bf16x8*)&Lc[boff + 0 * 512];
      bf16x8 q1 = *(const bf16x8*)&Lc[boff + 1 * 512];
      bf16x8 q2 = *(const bf16x8*)&Lc[boff + 2 * 512];
      bf16x8 q3 = *(const bf16x8*)&Lc[boff + 3 * 512];
      mfma_grp(Lc, aoff, q0, q1, q2, q3, acc);
    }
    cb = (cb == 2) ? 0 : cb + 1;
    sb = (sb == 2) ? 0 : sb + 1;
    const int t = g / 24;
    if (g - t * 24 == 23) {
      /* epilogue: BN + LIF + spike byte store; reseed acc = m*rcp */
      uint8_t* Sb = S + (size_t)br * M_ELEMS + (size_t)(t * 16 + b) * CN;
#pragma unroll
      for (int i = 0; i < 4; ++i) {
#pragma unroll
        for (int rg = 0; rg < 4; ++rg) {
          int c = rh * 128 + moff + i * 16 + quad * 4 + rg;
          float4 bn = *(const float4*)&bns[4 * (br * 256 + c)];
          float hsc = 0.5f * bn.x;
          float hsh = 0.5f * bn.y;
          float rcp = bn.z;
          uint8_t* row = Sb + (size_t)c * N_ + nt * 128 + noff + r;
#pragma unroll
          for (int j = 0; j < 4; ++j) {
            float m = acc[i * 4 + j][rg] * hsc + hsh;
            uint8_t s = (m >= 1.0f) ? 1 : 0;
            row[j * 16] = s;
            acc[i * 4 + j][rg] = s ? 0.f : m * rcp;
          }
        }
      }
    }
  }
}

/* ---- v spikes [T,B,C,N] u8 -> d_out v fp32 [T,B,H,N,D] ---- */
__global__ __launch_bounds__(256) void transpose_v(const uint8_t* __restrict__ SV, float* __restrict__ vout) {
  size_t o4 = ((size_t)blockIdx.x * 256 + threadIdx.x) * 4;
  int dd = (int)(o4 & 31);
  int n = (int)((o4 >> 5) & 1023);
  int h = (int)((o4 >> 15) & 7);
  int tb = (int)(o4 >> 18);
  const uint8_t* src = SV + (size_t)tb * CN + (size_t)(h * 32 + dd) * N_ + n;
  *(float4*)(vout + o4) = make_float4((float)src[0], (float)src[(size_t)N_],
                                      (float)src[2 * (size_t)N_], (float)src[3 * (size_t)N_]);
}

/* ---- kv gram via bitmask + popcount (exact integers in fp32) ---- */
__global__ __launch_bounds__(256) void kv_gram(const uint8_t* __restrict__ SK,
                                               const uint8_t* __restrict__ SV,
                                               float* __restrict__ KV) {
  __shared__ unsigned long long Kb[32][17];
  __shared__ unsigned long long Vb[32][17];
  const int tb = blockIdx.x >> 3, h = blockIdx.x & 7;
  const uint8_t* K = SK + (size_t)tb * CN + (size_t)h * 32 * N_;
  const uint8_t* V = SV + (size_t)tb * CN + (size_t)h * 32 * N_;
  const int tid = threadIdx.x;
  const int row = tid >> 3, c8 = tid & 7;
  uint8_t* Kb8 = (uint8_t*)&Kb[row][0];
  uint8_t* Vb8 = (uint8_t*)&Vb[row][0];
#pragma unroll
  for (int i = 0; i < 16; ++i) {
    int c = c8 + 8 * i;
    unsigned long long xk = *(const unsigned long long*)(K + (size_t)row * N_ + (size_t)c * 8);
    unsigned long long xv = *(const unsigned long long*)(V + (size_t)row * N_ + (size_t)c * 8);
    Kb8[c] = (uint8_t)((xk * 0x8040201008040201ull) >> 56);
    Vb8[c] = (uint8_t)((xv * 0x8040201008040201ull) >> 56);
  }
  __syncthreads();
  const int dd = tid >> 3, e0 = (tid & 7) * 4;
  int a0 = 0, a1 = 0, a2 = 0, a3 = 0;
#pragma unroll
  for (int c = 0; c < 16; ++c) {
    unsigned long long kd = Kb[dd][c];
    a0 += __popcll(kd & Vb[e0 + 0][c]);
    a1 += __popcll(kd & Vb[e0 + 1][c]);
    a2 += __popcll(kd & Vb[e0 + 2][c]);
    a3 += __popcll(kd & Vb[e0 + 3][c]);
  }
  float* o = KV + (size_t)(tb * 8 + h) * 1024 + dd * 32 + e0;
  o[0] = (float)a0; o[1] = (float)a1; o[2] = (float)a2; o[3] = (float)a3;
}

/* ---- fused attn + LIF(0.5) -> bf16 spikes Sc [tb][8 kb][1024 n][32 k] ---- */
__global__ __launch_bounds__(256) void attn_lif(const uint8_t* __restrict__ SQ,
                                                const float* __restrict__ KV,
                                                ushort_t* __restrict__ Sc) {
  __shared__ float kvs[1024];
  const int bid = blockIdx.x;
  const int nb = bid & 15, h = (bid >> 4) & 7, b = bid >> 7;
  const int n0 = nb * 64;
  const int tid = threadIdx.x;
  const int nl = tid & 63, eg = tid >> 6;
  float mem[8];
#pragma unroll
  for (int j = 0; j < 8; ++j) mem[j] = 0.f;
  for (int t = 0; t < 4; ++t) {
    const float* kvp = KV + (size_t)((t * B_ + b) * 8 + h) * 1024;
    *(float4*)&kvs[tid * 4] = *(const float4*)&kvp[tid * 4];
    __syncthreads();
    const uint8_t* q = SQ + (size_t)(t * B_ + b) * CN + (size_t)h * 32 * N_ + n0 + nl;
    float val[8];
#pragma unroll
    for (int j = 0; j < 8; ++j) val[j] = 0.f;
#pragma unroll 4
    for (int dd = 0; dd < 32; ++dd) {
      float qv = (float)q[(size_t)dd * N_];
#pragma unroll
      for (int j = 0; j < 8; ++j) val[j] += qv * kvs[dd * 32 + eg * 8 + j];
    }
    ushort_t pk[8];
#pragma unroll
    for (int j = 0; j < 8; ++j) {
      float a = val[j] * 0.125f;
      mem[j] += (a - mem[j]) * 0.5f;
      int s = (mem[j] >= 0.5f);
      pk[j] = s ? (ushort_t)0x3F80 : (ushort_t)0;
      if (s) mem[j] = 0.f;
    }
    uint4 o;
    o.x = (u32)pk[0] | ((u32)pk[1] << 16);
    o.y = (u32)pk[2] | ((u32)pk[3] << 16);
    o.z = (u32)pk[4] | ((u32)pk[5] << 16);
    o.w = (u32)pk[6] | ((u32)pk[7] << 16);
    *(uint4*)(Sc + ((size_t)((t * B_ + b) * 8 + h) * 1024 + n0 + nl) * 32 + eg * 8) = o;
    __syncthreads();
  }
}

/* ---- p projection MFMA GEMM (K'=512, 2-term split) + BN + final LIF(1.0) -> out fp32 spikes.
   grid (8 nt, 2 mt, 16 b); same 3-buffer counted-vmcnt pipeline; 64 chunks. ---- */
__global__ __launch_bounds__(256, 3) void gemm_p_lif(
    const ushort_t* __restrict__ Wpc, const ushort_t* __restrict__ Sc,
    const float* __restrict__ bns, float* __restrict__ out) {
  __shared__ ushort_t L[3][8192];
  const int nt = blockIdx.x, mt = blockIdx.y, b = blockIdx.z;
  const ushort_t* Ab = Wpc + (size_t)(mt * 128) * 512;
  const int tid = threadIdx.x;
  const int lane = tid & 63;
  const int quad = lane >> 4, r = lane & 15;
  const int w = tid >> 6;
  const int moff = (w & 1) * 64, noff = (w >> 1) * 64;
  const int c0 = tid, c1 = tid + 256;
  const int s0 = SWZ(c0), s1 = SWZ(c1);
  const int qx = quad ^ (r & 3) ^ ((r >> 2) & 3);
  const int aoff = (moff + r) * 32 + qx * 8;
  const int boff = 4096 + (noff + r) * 32 + qx * 8;

  auto STAGE = [&](int gS, int bi) {
    const int tS = gS >> 4;
    const int jS = gS & 15;
    const ushort_t* Acol = Ab + jS * 32;                      /* [hi|lo] cols */
    const int slab = jS & 7;
    const ushort_t* Bb = Sc + ((size_t)(tS * 16 + b) * 8 + slab) * 32768 +
                         (size_t)(nt * 128) * 32;
    ushort_t* Lb = &L[bi][0];
    async_copy16(Acol + (size_t)(c0 >> 2) * 512 + (s0 & 3) * 8, Lb + c0 * 8);
    async_copy16(Acol + (size_t)(c1 >> 2) * 512 + (s1 & 3) * 8, Lb + c1 * 8);
    async_copy16(Bb + s0 * 8, Lb + 4096 + c0 * 8);
    async_copy16(Bb + s1 * 8, Lb + 4096 + c1 * 8);
  };

  f32x4 acc[16];
#pragma unroll
  for (int f = 0; f < 16; ++f) acc[f] = (f32x4){0.f, 0.f, 0.f, 0.f};

  STAGE(0, 0);
  STAGE(1, 1);
  int cb = 0, sb = 2;

#pragma unroll 1
  for (int g = 0; g < 64; ++g) {
    __builtin_amdgcn_s_barrier();
    __builtin_amdgcn_sched_barrier(0);
    if (g < 62) STAGE(g + 2, sb);
    if (g < 62)      { WAITV(8); }
    else if (g == 62){ WAITV(4); }
    else             { WAITV(0); }
    __builtin_amdgcn_s_barrier();
    __builtin_amdgcn_sched_barrier(0);
    {
      const ushort_t* Lc = &L[cb][0];
      bf16x8 q0 = *(const bf16x8*)&Lc[boff + 0 * 512];
      bf16x8 q1 = *(const bf16x8*)&Lc[boff + 1 * 512];
      bf16x8 q2 = *(const bf16x8*)&Lc[boff + 2 * 512];
      bf16x8 q3 = *(const bf16x8*)&Lc[boff + 3 * 512];
      mfma_grp(Lc, aoff, q0, q1, q2, q3, acc);
    }
    cb = (cb == 2) ? 0 : cb + 1;
    sb = (sb == 2) ? 0 : sb + 1;
    if ((g & 15) == 15) {
      const int t = g >> 4;
      float* Ob = out + (size_t)(t * 16 + b) * CN;
#pragma unroll
      for (int i = 0; i < 4; ++i) {
#pragma unroll
        for (int rg = 0; rg < 4; ++rg) {
          int c = mt * 128 + moff + i * 16 + quad * 4 + rg;
          float4 bn = *(const float4*)&bns[4 * (768 + c)];
          float hsc = 0.5f * bn.x;
          float hsh = 0.5f * bn.y;
          float rcp = bn.z;
          float* row2 = Ob + (size_t)c * N_ + nt * 128 + noff + r;
#pragma unroll
          for (int j = 0; j < 4; ++j) {
            float m = acc[i * 4 + j][rg] * hsc + hsh;
            int s = (m >= 1.0f);
            row2[j * 16] = s ? 1.0f : 0.0f;
            acc[i * 4 + j][rg] = s ? 0.f : m * rcp;
          }
        }
      }
    }
  }
}

extern "C" void kernel_launch(void* const* d_in, const int* in_sizes, int n_in,
                              void* d_out, int out_size, void* d_ws, size_t ws_size,
                              hipStream_t stream) {
  const float* x   = (const float*)d_in[0];
  const float* qw  = (const float*)d_in[2];
  const float* qg  = (const float*)d_in[3];
  const float* qb  = (const float*)d_in[4];
  const float* qm  = (const float*)d_in[5];
  const float* qv  = (const float*)d_in[6];
  const float* kw  = (const float*)d_in[7];
  const float* kg  = (const float*)d_in[8];
  const float* kb  = (const float*)d_in[9];
  const float* km  = (const float*)d_in[10];
  const float* kvv = (const float*)d_in[11];
  const float* vw  = (const float*)d_in[12];
  const float* vg  = (const float*)d_in[13];
  const float* vb  = (const float*)d_in[14];
  const float* vm  = (const float*)d_in[15];
  const float* vv  = (const float*)d_in[16];
  const float* pw  = (const float*)d_in[17];
  const float* pb  = (const float*)d_in[18];
  const float* pg  = (const float*)d_in[19];
  const float* pbt = (const float*)d_in[20];
  const float* pm  = (const float*)d_in[21];
  const float* pv  = (const float*)d_in[22];

  float* out = (float*)d_out;
  float* vout = out + M_ELEMS;

  uint8_t* ws = (uint8_t*)d_ws;
  uint8_t* S   = ws + OFF_S;          /* SQ | SK | SV */
  ushort_t* Xc = (ushort_t*)(ws + OFF_XC);
  ushort_t* Sc = (ushort_t*)(ws + OFF_SC);
  float* KV    = (float*)(ws + OFF_KV);
  float* BNS   = (float*)(ws + OFF_BNS);
  ushort_t* Wc  = (ushort_t*)(ws + OFF_WC);
  ushort_t* Wpc = (ushort_t*)(ws + OFF_WPC);

  bn_prep<<<dim3(1), dim3(1024), 0, stream>>>(qg, qb, qm, qv, kg, kb, km, kvv,
                                              vg, vb, vm, vv, pb, pg, pbt, pm, pv, BNS);
  convert_w<<<dim3(1024), dim3(256), 0, stream>>>(qw, kw, vw, pw, Wc, Wpc);
  convert_x<<<dim3(2048), dim3(256), 0, stream>>>(x, Xc);
  gemm_qkv_lif<<<dim3(8, 6, 16), dim3(256), 0, stream>>>(Wc, Xc, BNS, S);
  transpose_v<<<dim3(16384), dim3(256), 0, stream>>>(S + 2ull * M_ELEMS, vout);
  kv_gram<<<dim3(512), dim3(256), 0, stream>>>(S + 1ull * M_ELEMS, S + 2ull * M_ELEMS, KV);
  attn_lif<<<dim3(2048), dim3(256), 0, stream>>>(S, KV, Sc);
  gemm_p_lif<<<dim3(8, 2, 16), dim3(256), 0, stream>>>(Wpc, Sc, BNS, out);
}

// Round 7
// 391.927 us; speedup vs baseline: 1.0667x; 1.0667x over previous
//
#include <hip/hip_runtime.h>
#include <stdint.h>

typedef unsigned int u32;
typedef unsigned short ushort_t;

#define T_ 4
#define B_ 16
#define C_ 256
#define N_ 1024
#define CN (C_ * N_)                 /* 262144 */
#define M_ELEMS (64 * C_ * N_)       /* 16777216 elems per [TB,C,N] tensor */

/* workspace byte offsets (ws >= ~138 MB) */
#define OFF_S    0ull                          /* SQ,SK,SV u8: 3*16.7MB */
#define OFF_XC   67108864ull                   /* Xc bf16 [64 tb][16 slab][1024 n][32 k] = 64MB; later aliased by Sc */
#define OFF_SC   67108864ull                   /* Sc bf16 [64 tb][8 kb][1024 n][32 k] = 32MB */
#define OFF_KV   134217728ull                  /* fp32 [64][8][32][32] = 2MB */
#define OFF_BNS  136314880ull                  /* float4 per channel-slot: 1024*16B = 16KB */
#define OFF_WC   136331264ull                  /* Wc bf16 [3][256][768] = 1.125MB */
#define OFF_WPC  137510912ull                  /* Wpc bf16 [256][512] = 256KB */

typedef __attribute__((ext_vector_type(8))) short bf16x8;
typedef __attribute__((ext_vector_type(4))) float f32x4;

/* XOR swizzle of 16B slots within a 64B LDS row (kept from R5). */
#define SWZ(c) (((c) & ~3) | (((c) & 3) ^ (((c) >> 2) & 3) ^ (((c) >> 4) & 3)))

__device__ __forceinline__ ushort_t f2bf(float f) {
  u32 u = __float_as_uint(f);
  u32 r = (u + 0x7FFFu + ((u >> 16) & 1u)) >> 16;
  return (ushort_t)r;
}
__device__ __forceinline__ float bf2f(ushort_t h) { return __uint_as_float((u32)h << 16); }

__device__ __forceinline__ void async_copy16(const void* g, void* l) {
  __builtin_amdgcn_global_load_lds(
      (const __attribute__((address_space(1))) u32*)g,
      (__attribute__((address_space(3))) u32*)l, 16, 0, 0);
}

/* 16-MFMA group: 4 a-frags from Ap against 4 preloaded b-frags, accumulate acc[0..15] */
__device__ __forceinline__ void mfma_grp(const ushort_t* Ap, int aoff,
                                         bf16x8 b0, bf16x8 b1, bf16x8 b2, bf16x8 b3,
                                         f32x4* acc) {
  bf16x8 a0 = *(const bf16x8*)&Ap[aoff + 0 * 16 * 32];
  bf16x8 a1 = *(const bf16x8*)&Ap[aoff + 1 * 16 * 32];
  bf16x8 a2 = *(const bf16x8*)&Ap[aoff + 2 * 16 * 32];
  bf16x8 a3 = *(const bf16x8*)&Ap[aoff + 3 * 16 * 32];
  acc[0]  = __builtin_amdgcn_mfma_f32_16x16x32_bf16(a0, b0, acc[0],  0, 0, 0);
  acc[1]  = __builtin_amdgcn_mfma_f32_16x16x32_bf16(a0, b1, acc[1],  0, 0, 0);
  acc[2]  = __builtin_amdgcn_mfma_f32_16x16x32_bf16(a0, b2, acc[2],  0, 0, 0);
  acc[3]  = __builtin_amdgcn_mfma_f32_16x16x32_bf16(a0, b3, acc[3],  0, 0, 0);
  acc[4]  = __builtin_amdgcn_mfma_f32_16x16x32_bf16(a1, b0, acc[4],  0, 0, 0);
  acc[5]  = __builtin_amdgcn_mfma_f32_16x16x32_bf16(a1, b1, acc[5],  0, 0, 0);
  acc[6]  = __builtin_amdgcn_mfma_f32_16x16x32_bf16(a1, b2, acc[6],  0, 0, 0);
  acc[7]  = __builtin_amdgcn_mfma_f32_16x16x32_bf16(a1, b3, acc[7],  0, 0, 0);
  acc[8]  = __builtin_amdgcn_mfma_f32_16x16x32_bf16(a2, b0, acc[8],  0, 0, 0);
  acc[9]  = __builtin_amdgcn_mfma_f32_16x16x32_bf16(a2, b1, acc[9],  0, 0, 0);
  acc[10] = __builtin_amdgcn_mfma_f32_16x16x32_bf16(a2, b2, acc[10], 0, 0, 0);
  acc[11] = __builtin_amdgcn_mfma_f32_16x16x32_bf16(a2, b3, acc[11], 0, 0, 0);
  acc[12] = __builtin_amdgcn_mfma_f32_16x16x32_bf16(a3, b0, acc[12], 0, 0, 0);
  acc[13] = __builtin_amdgcn_mfma_f32_16x16x32_bf16(a3, b1, acc[13], 0, 0, 0);
  acc[14] = __builtin_amdgcn_mfma_f32_16x16x32_bf16(a3, b2, acc[14], 0, 0, 0);
  acc[15] = __builtin_amdgcn_mfma_f32_16x16x32_bf16(a3, b3, acc[15], 0, 0, 0);
}

/* ---- BN coefficient prep: per channel-slot float4 {sc, shift, 1/sc, 0} ---- */
__global__ void bn_prep(const float* __restrict__ qg, const float* __restrict__ qb2, const float* __restrict__ qm, const float* __restrict__ qv,
                        const float* __restrict__ kg, const float* __restrict__ kb, const float* __restrict__ km, const float* __restrict__ kvv,
                        const float* __restrict__ vg, const float* __restrict__ vb, const float* __restrict__ vm, const float* __restrict__ vv,
                        const float* __restrict__ pbias,
                        const float* __restrict__ pg, const float* __restrict__ pbt, const float* __restrict__ pm, const float* __restrict__ pv,
                        float* __restrict__ bns) {
  int i = threadIdx.x;  /* 1024 threads */
  int br = i >> 8, c = i & 255;
  const float *g, *bt, *m, *v;
  float bias = 0.f;
  if (br == 0)      { g = qg; bt = qb2; m = qm; v = qv; }
  else if (br == 1) { g = kg; bt = kb;  m = km; v = kvv; }
  else if (br == 2) { g = vg; bt = vb;  m = vm; v = vv; }
  else              { g = pg; bt = pbt; m = pm; v = pv; bias = pbias[c]; }
  float sc = g[c] / sqrtf(v[c] + 1e-5f);
  float sh = bt[c] + (bias - m[c]) * sc;
  float rcp = (sc != 0.f) ? (1.f / sc) : 0.f;
  *(float4*)&bns[4 * i] = make_float4(sc, sh, rcp, 0.f);
}

/* ---- split weights to bf16 hi/lo. Wc[br][256][768] = [hi|lo|hi]; Wpc[256][512] = [hi|lo] ---- */
__global__ __launch_bounds__(256) void convert_w(const float* __restrict__ qw, const float* __restrict__ kw,
                                                 const float* __restrict__ vw, const float* __restrict__ pw,
                                                 ushort_t* __restrict__ Wc, ushort_t* __restrict__ Wpc) {
  int id = blockIdx.x * 256 + threadIdx.x;   /* 4*65536 */
  int br = id >> 16, o = (id >> 8) & 255, c = id & 255;
  const float* w = (br == 0) ? qw : (br == 1) ? kw : (br == 2) ? vw : pw;
  float f = w[o * 256 + c];
  ushort_t hi = f2bf(f);
  ushort_t lo = f2bf(f - bf2f(hi));
  if (br < 3) {
    ushort_t* d = Wc + (size_t)br * 196608 + (size_t)o * 768 + c;
    d[0] = hi; d[256] = lo; d[512] = hi;
  } else {
    ushort_t* d = Wpc + (size_t)o * 512 + c;
    d[0] = hi; d[256] = lo;
  }
}

/* ---- x fp32 [tb][256 c][1024 n] -> Xc bf16 [tb][16 slab][1024 n][32 k]; slab kb<8 = hi, 8+kb = lo ---- */
__global__ __launch_bounds__(256) void convert_x(const float* __restrict__ x, ushort_t* __restrict__ Xc) {
  __shared__ ushort_t hi[32][260];
  __shared__ ushort_t lo[32][260];
  int bid = blockIdx.x;
  int nc = bid & 3, kb = (bid >> 2) & 7, tb = bid >> 5;
  int t = threadIdx.x;
  int n0 = nc * 256;
  const float* xb = x + (size_t)tb * CN + (size_t)(kb * 32) * N_ + n0;
#pragma unroll
  for (int p = 0; p < 8; ++p) {
    int k = p * 4 + (t >> 6);
    int n4 = (t & 63) * 4;
    float4 v = *(const float4*)&xb[(size_t)k * N_ + n4];
    ushort_t h0 = f2bf(v.x), h1 = f2bf(v.y), h2 = f2bf(v.z), h3 = f2bf(v.w);
    short4 hv = make_short4((short)h0, (short)h1, (short)h2, (short)h3);
    short4 lv = make_short4((short)f2bf(v.x - bf2f(h0)), (short)f2bf(v.y - bf2f(h1)),
                            (short)f2bf(v.z - bf2f(h2)), (short)f2bf(v.w - bf2f(h3)));
    *(short4*)&hi[k][n4] = hv;
    *(short4*)&lo[k][n4] = lv;
  }
  __syncthreads();
  ushort_t* Hs = Xc + ((size_t)(tb * 16 + kb) * 1024 + n0) * 32;
  ushort_t* Ls = Xc + ((size_t)(tb * 16 + 8 + kb) * 1024 + n0) * 32;
  int kq = t & 3;
#pragma unroll
  for (int q = 0; q < 4; ++q) {
    int n = q * 64 + (t >> 2);
    u32 a0 = (u32)hi[kq * 8 + 0][n] | ((u32)hi[kq * 8 + 1][n] << 16);
    u32 a1 = (u32)hi[kq * 8 + 2][n] | ((u32)hi[kq * 8 + 3][n] << 16);
    u32 a2 = (u32)hi[kq * 8 + 4][n] | ((u32)hi[kq * 8 + 5][n] << 16);
    u32 a3 = (u32)hi[kq * 8 + 6][n] | ((u32)hi[kq * 8 + 7][n] << 16);
    *(uint4*)(Hs + (size_t)n * 32 + kq * 8) = make_uint4(a0, a1, a2, a3);
    u32 b0 = (u32)lo[kq * 8 + 0][n] | ((u32)lo[kq * 8 + 1][n] << 16);
    u32 b1 = (u32)lo[kq * 8 + 2][n] | ((u32)lo[kq * 8 + 3][n] << 16);
    u32 b2 = (u32)lo[kq * 8 + 4][n] | ((u32)lo[kq * 8 + 5][n] << 16);
    u32 b3 = (u32)lo[kq * 8 + 6][n] | ((u32)lo[kq * 8 + 7][n] << 16);
    *(uint4*)(Ls + (size_t)n * 32 + kq * 8) = make_uint4(b0, b1, b2, b3);
  }
}

/* ---- fused q/k/v MFMA GEMM (K'=768 bf16-split) + BN + LIF -> u8 spikes. (R5 form, reverted) ---- */
__global__ __launch_bounds__(256, 3) void gemm_qkv_lif(
    const ushort_t* __restrict__ Wc, const ushort_t* __restrict__ Xc,
    const float* __restrict__ bns, uint8_t* __restrict__ S) {
  __shared__ ushort_t Ah[2][4096];   /* A_hi, persists across both halves of a round */
  __shared__ ushort_t Xl[2][4096];   /* A_lo, then overwritten by B_lo */
  __shared__ ushort_t Bh[2][4096];   /* B_hi */
  const int nt = blockIdx.x, mt = blockIdx.y, b = blockIdx.z;
  const int br = mt >> 1, rh = mt & 1;
  const ushort_t* Ab = Wc + (size_t)br * 196608 + (size_t)(rh * 128) * 768;
  const int tid = threadIdx.x;
  const int lane = tid & 63;
  const int quad = lane >> 4, r = lane & 15;
  const int w = tid >> 6;
  const int moff = (w & 1) * 64, noff = (w >> 1) * 64;
  const int c0 = tid, c1 = tid + 256;       /* staging chunk ids (linear LDS dest) */
  const int s0 = SWZ(c0), s1 = SWZ(c1);     /* swizzled source slots */
  const int qx = quad ^ (r & 3) ^ ((r >> 2) & 3);  /* read-side slot XOR */
  const int aoff = (moff + r) * 32 + qx * 8;
  const int boff = (noff + r) * 32 + qx * 8;

  f32x4 acc[16];
#pragma unroll
  for (int f = 0; f < 16; ++f) acc[f] = (f32x4){0.f, 0.f, 0.f, 0.f};

  for (int t = 0; t < 4; ++t) {
    const ushort_t* Xtb = Xc + (size_t)(t * 16 + b) * 16 * 32768 + (size_t)(nt * 128) * 32;
    for (int p = 0; p < 4; ++p) {
      const ushort_t* AcH = Ab + p * 64;          /* W_hi cols p*64.. */
      const ushort_t* AcL = Ab + 256 + p * 64;    /* W_lo cols        */
      const ushort_t* Bh0 = Xtb + (size_t)(2 * p) * 32768;      /* X_hi slabs 2p,2p+1 */
      const ushort_t* Bh1 = Bh0 + 32768;
      async_copy16(AcH + (size_t)(c0 >> 2) * 768 + (s0 & 3) * 8,      &Ah[0][c0 * 8]);
      async_copy16(AcH + (size_t)(c1 >> 2) * 768 + (s1 & 3) * 8,      &Ah[0][c1 * 8]);
      async_copy16(AcH + (size_t)(c0 >> 2) * 768 + 32 + (s0 & 3) * 8, &Ah[1][c0 * 8]);
      async_copy16(AcH + (size_t)(c1 >> 2) * 768 + 32 + (s1 & 3) * 8, &Ah[1][c1 * 8]);
      async_copy16(AcL + (size_t)(c0 >> 2) * 768 + (s0 & 3) * 8,      &Xl[0][c0 * 8]);
      async_copy16(AcL + (size_t)(c1 >> 2) * 768 + (s1 & 3) * 8,      &Xl[0][c1 * 8]);
      async_copy16(AcL + (size_t)(c0 >> 2) * 768 + 32 + (s0 & 3) * 8, &Xl[1][c0 * 8]);
      async_copy16(AcL + (size_t)(c1 >> 2) * 768 + 32 + (s1 & 3) * 8, &Xl[1][c1 * 8]);
      async_copy16(Bh0 + s0 * 8, &Bh[0][c0 * 8]);
      async_copy16(Bh0 + s1 * 8, &Bh[0][c1 * 8]);
      async_copy16(Bh1 + s0 * 8, &Bh[1][c0 * 8]);
      async_copy16(Bh1 + s1 * 8, &Bh[1][c1 * 8]);
      __syncthreads();
      {
        bf16x8 b0 = *(const bf16x8*)&Bh[0][boff + 0 * 16 * 32];
        bf16x8 b1 = *(const bf16x8*)&Bh[0][boff + 1 * 16 * 32];
        bf16x8 b2 = *(const bf16x8*)&Bh[0][boff + 2 * 16 * 32];
        bf16x8 b3 = *(const bf16x8*)&Bh[0][boff + 3 * 16 * 32];
        mfma_grp(&Ah[0][0], aoff, b0, b1, b2, b3, acc);
        mfma_grp(&Xl[0][0], aoff, b0, b1, b2, b3, acc);
      }
      {
        bf16x8 b0 = *(const bf16x8*)&Bh[1][boff + 0 * 16 * 32];
        bf16x8 b1 = *(const bf16x8*)&Bh[1][boff + 1 * 16 * 32];
        bf16x8 b2 = *(const bf16x8*)&Bh[1][boff + 2 * 16 * 32];
        bf16x8 b3 = *(const bf16x8*)&Bh[1][boff + 3 * 16 * 32];
        mfma_grp(&Ah[1][0], aoff, b0, b1, b2, b3, acc);
        mfma_grp(&Xl[1][0], aoff, b0, b1, b2, b3, acc);
      }
      __syncthreads();
      const ushort_t* Bl0 = Xtb + (size_t)(8 + 2 * p) * 32768;
      const ushort_t* Bl1 = Bl0 + 32768;
      async_copy16(Bl0 + s0 * 8, &Xl[0][c0 * 8]);
      async_copy16(Bl0 + s1 * 8, &Xl[0][c1 * 8]);
      async_copy16(Bl1 + s0 * 8, &Xl[1][c0 * 8]);
      async_copy16(Bl1 + s1 * 8, &Xl[1][c1 * 8]);
      __syncthreads();
      {
        bf16x8 b0 = *(const bf16x8*)&Xl[0][boff + 0 * 16 * 32];
        bf16x8 b1 = *(const bf16x8*)&Xl[0][boff + 1 * 16 * 32];
        bf16x8 b2 = *(const bf16x8*)&Xl[0][boff + 2 * 16 * 32];
        bf16x8 b3 = *(const bf16x8*)&Xl[0][boff + 3 * 16 * 32];
        mfma_grp(&Ah[0][0], aoff, b0, b1, b2, b3, acc);
      }
      {
        bf16x8 b0 = *(const bf16x8*)&Xl[1][boff + 0 * 16 * 32];
        bf16x8 b1 = *(const bf16x8*)&Xl[1][boff + 1 * 16 * 32];
        bf16x8 b2 = *(const bf16x8*)&Xl[1][boff + 2 * 16 * 32];
        bf16x8 b3 = *(const bf16x8*)&Xl[1][boff + 3 * 16 * 32];
        mfma_grp(&Ah[1][0], aoff, b0, b1, b2, b3, acc);
      }
      __syncthreads();
    }
    /* epilogue: BN + LIF step + spike byte store; re-seed acc with m_carry/sc */
    uint8_t* Sb = S + (size_t)br * M_ELEMS + (size_t)(t * 16 + b) * CN;
#pragma unroll
    for (int i = 0; i < 4; ++i) {
#pragma unroll
      for (int rg = 0; rg < 4; ++rg) {
        int c = rh * 128 + moff + i * 16 + quad * 4 + rg;
        float4 bn = *(const float4*)&bns[4 * (br * 256 + c)];
        float hsc = 0.5f * bn.x;
        float hsh = 0.5f * bn.y;
        float rcp = bn.z;
        uint8_t* row = Sb + (size_t)c * N_ + nt * 128 + noff + r;
#pragma unroll
        for (int j = 0; j < 4; ++j) {
          float m = acc[i * 4 + j][rg] * hsc + hsh;
          uint8_t s = (m >= 1.0f) ? 1 : 0;
          row[j * 16] = s;
          acc[i * 4 + j][rg] = s ? 0.f : m * rcp;
        }
      }
    }
  }
}

/* ---- kv gram (bitmask popcount) + vout emission from the V bitmask.
   Bit mapping of multiply-gather: bit j of packed byte c <-> n = c*8 + (7-j).
   vout[tb][h][n][dd] written as coalesced float4 (4 dd per thread). ---- */
__global__ __launch_bounds__(256) void kv_gram_tv(const uint8_t* __restrict__ SK,
                                                  const uint8_t* __restrict__ SV,
                                                  float* __restrict__ KV,
                                                  float* __restrict__ vout) {
  __shared__ unsigned long long Kb[32][17];
  __shared__ unsigned long long Vb[32][17];
  const int tb = blockIdx.x >> 3, h = blockIdx.x & 7;
  const uint8_t* K = SK + (size_t)tb * CN + (size_t)h * 32 * N_;
  const uint8_t* V = SV + (size_t)tb * CN + (size_t)h * 32 * N_;
  const int tid = threadIdx.x;
  const int row = tid >> 3, c8 = tid & 7;
  uint8_t* Kb8 = (uint8_t*)&Kb[row][0];
  uint8_t* Vb8 = (uint8_t*)&Vb[row][0];
#pragma unroll
  for (int i = 0; i < 16; ++i) {
    int c = c8 + 8 * i;
    unsigned long long xk = *(const unsigned long long*)(K + (size_t)row * N_ + (size_t)c * 8);
    unsigned long long xv = *(const unsigned long long*)(V + (size_t)row * N_ + (size_t)c * 8);
    Kb8[c] = (uint8_t)((xk * 0x8040201008040201ull) >> 56);
    Vb8[c] = (uint8_t)((xv * 0x8040201008040201ull) >> 56);
  }
  __syncthreads();
  /* gram */
  {
    const int dd = tid >> 3, e0 = (tid & 7) * 4;
    int a0 = 0, a1 = 0, a2 = 0, a3 = 0;
#pragma unroll
    for (int c = 0; c < 16; ++c) {
      unsigned long long kd = Kb[dd][c];
      a0 += __popcll(kd & Vb[e0 + 0][c]);
      a1 += __popcll(kd & Vb[e0 + 1][c]);
      a2 += __popcll(kd & Vb[e0 + 2][c]);
      a3 += __popcll(kd & Vb[e0 + 3][c]);
    }
    float* o = KV + (size_t)(tb * 8 + h) * 1024 + dd * 32 + e0;
    o[0] = (float)a0; o[1] = (float)a1; o[2] = (float)a2; o[3] = (float)a3;
  }
  /* vout: [tb][h][n][dd] fp32 spikes from Vb bits */
  float* vo = vout + ((size_t)tb * 8 + h) * (size_t)(1024 * 32);
  const int sn = tid >> 3;           /* n offset within each 32-block */
  const int dd0 = (tid & 7) * 4;
#pragma unroll 4
  for (int it = 0; it < 32; ++it) {
    int n = it * 32 + sn;
    int wi = n >> 6;
    int bit = ((n >> 3) & 7) * 8 + 7 - (n & 7);
    float4 v4;
    v4.x = ((Vb[dd0 + 0][wi] >> bit) & 1ull) ? 1.0f : 0.0f;
    v4.y = ((Vb[dd0 + 1][wi] >> bit) & 1ull) ? 1.0f : 0.0f;
    v4.z = ((Vb[dd0 + 2][wi] >> bit) & 1ull) ? 1.0f : 0.0f;
    v4.w = ((Vb[dd0 + 3][wi] >> bit) & 1ull) ? 1.0f : 0.0f;
    *(float4*)(vo + (size_t)n * 32 + dd0) = v4;
  }
}

/* ---- fused attn + LIF(0.5) -> bf16 spikes Sc; kvs reads vectorized to float4 ---- */
__global__ __launch_bounds__(256) void attn_lif(const uint8_t* __restrict__ SQ,
                                                const float* __restrict__ KV,
                                                ushort_t* __restrict__ Sc) {
  __shared__ float kvs[1024];
  const int bid = blockIdx.x;
  const int nb = bid & 15, h = (bid >> 4) & 7, b = bid >> 7;
  const int n0 = nb * 64;
  const int tid = threadIdx.x;
  const int nl = tid & 63, eg = tid >> 6;
  float mem[8];
#pragma unroll
  for (int j = 0; j < 8; ++j) mem[j] = 0.f;
  for (int t = 0; t < 4; ++t) {
    const float* kvp = KV + (size_t)((t * B_ + b) * 8 + h) * 1024;
    *(float4*)&kvs[tid * 4] = *(const float4*)&kvp[tid * 4];
    __syncthreads();
    const uint8_t* q = SQ + (size_t)(t * B_ + b) * CN + (size_t)h * 32 * N_ + n0 + nl;
    float val[8];
#pragma unroll
    for (int j = 0; j < 8; ++j) val[j] = 0.f;
#pragma unroll 4
    for (int dd = 0; dd < 32; ++dd) {
      float qv = (float)q[(size_t)dd * N_];
      float4 ka = *(const float4*)&kvs[dd * 32 + eg * 8];
      float4 kb2 = *(const float4*)&kvs[dd * 32 + eg * 8 + 4];
      val[0] += qv * ka.x;  val[1] += qv * ka.y;  val[2] += qv * ka.z;  val[3] += qv * ka.w;
      val[4] += qv * kb2.x; val[5] += qv * kb2.y; val[6] += qv * kb2.z; val[7] += qv * kb2.w;
    }
    ushort_t pk[8];
#pragma unroll
    for (int j = 0; j < 8; ++j) {
      float a = val[j] * 0.125f;
      mem[j] += (a - mem[j]) * 0.5f;
      int s = (mem[j] >= 0.5f);
      pk[j] = s ? (ushort_t)0x3F80 : (ushort_t)0;
      if (s) mem[j] = 0.f;
    }
    uint4 o;
    o.x = (u32)pk[0] | ((u32)pk[1] << 16);
    o.y = (u32)pk[2] | ((u32)pk[3] << 16);
    o.z = (u32)pk[4] | ((u32)pk[5] << 16);
    o.w = (u32)pk[6] | ((u32)pk[7] << 16);
    *(uint4*)(Sc + ((size_t)((t * B_ + b) * 8 + h) * 1024 + n0 + nl) * 32 + eg * 8) = o;
    __syncthreads();
  }
}

/* ---- p projection MFMA GEMM (K'=512, 2-term split) + BN + final LIF(1.0) -> out fp32 spikes.
   (R5 form, reverted) ---- */
__global__ __launch_bounds__(256, 3) void gemm_p_lif(
    const ushort_t* __restrict__ Wpc, const ushort_t* __restrict__ Sc,
    const float* __restrict__ bns, float* __restrict__ out) {
  __shared__ ushort_t Ah[2][4096];
  __shared__ ushort_t Al[2][4096];
  __shared__ ushort_t Bs[2][4096];
  const int nt = blockIdx.x, mt = blockIdx.y, b = blockIdx.z;
  const ushort_t* Ab = Wpc + (size_t)(mt * 128) * 512;
  const int tid = threadIdx.x;
  const int lane = tid & 63;
  const int quad = lane >> 4, r = lane & 15;
  const int w = tid >> 6;
  const int moff = (w & 1) * 64, noff = (w >> 1) * 64;
  const int c0 = tid, c1 = tid + 256;
  const int s0 = SWZ(c0), s1 = SWZ(c1);
  const int qx = quad ^ (r & 3) ^ ((r >> 2) & 3);
  const int aoff = (moff + r) * 32 + qx * 8;
  const int boff = (noff + r) * 32 + qx * 8;
  f32x4 acc[16];
#pragma unroll
  for (int f = 0; f < 16; ++f) acc[f] = (f32x4){0.f, 0.f, 0.f, 0.f};

  for (int t = 0; t < 4; ++t) {
    const ushort_t* Stb = Sc + (size_t)(t * 16 + b) * 8 * 32768 + (size_t)(nt * 128) * 32;
    for (int p = 0; p < 4; ++p) {
      const ushort_t* AcH = Ab + p * 64;
      const ushort_t* AcL = Ab + 256 + p * 64;
      const ushort_t* Bb0 = Stb + (size_t)(2 * p) * 32768;
      const ushort_t* Bb1 = Bb0 + 32768;
      async_copy16(AcH + (size_t)(c0 >> 2) * 512 + (s0 & 3) * 8,      &Ah[0][c0 * 8]);
      async_copy16(AcH + (size_t)(c1 >> 2) * 512 + (s1 & 3) * 8,      &Ah[0][c1 * 8]);
      async_copy16(AcH + (size_t)(c0 >> 2) * 512 + 32 + (s0 & 3) * 8, &Ah[1][c0 * 8]);
      async_copy16(AcH + (size_t)(c1 >> 2) * 512 + 32 + (s1 & 3) * 8, &Ah[1][c1 * 8]);
      async_copy16(AcL + (size_t)(c0 >> 2) * 512 + (s0 & 3) * 8,      &Al[0][c0 * 8]);
      async_copy16(AcL + (size_t)(c1 >> 2) * 512 + (s1 & 3) * 8,      &Al[0][c1 * 8]);
      async_copy16(AcL + (size_t)(c0 >> 2) * 512 + 32 + (s0 & 3) * 8, &Al[1][c0 * 8]);
      async_copy16(AcL + (size_t)(c1 >> 2) * 512 + 32 + (s1 & 3) * 8, &Al[1][c1 * 8]);
      async_copy16(Bb0 + s0 * 8, &Bs[0][c0 * 8]);
      async_copy16(Bb0 + s1 * 8, &Bs[0][c1 * 8]);
      async_copy16(Bb1 + s0 * 8, &Bs[1][c0 * 8]);
      async_copy16(Bb1 + s1 * 8, &Bs[1][c1 * 8]);
      __syncthreads();
      {
        bf16x8 b0 = *(const bf16x8*)&Bs[0][boff + 0 * 16 * 32];
        bf16x8 b1 = *(const bf16x8*)&Bs[0][boff + 1 * 16 * 32];
        bf16x8 b2 = *(const bf16x8*)&Bs[0][boff + 2 * 16 * 32];
        bf16x8 b3 = *(const bf16x8*)&Bs[0][boff + 3 * 16 * 32];
        mfma_grp(&Ah[0][0], aoff, b0, b1, b2, b3, acc);
        mfma_grp(&Al[0][0], aoff, b0, b1, b2, b3, acc);
      }
      {
        bf16x8 b0 = *(const bf16x8*)&Bs[1][boff + 0 * 16 * 32];
        bf16x8 b1 = *(const bf16x8*)&Bs[1][boff + 1 * 16 * 32];
        bf16x8 b2 = *(const bf16x8*)&Bs[1][boff + 2 * 16 * 32];
        bf16x8 b3 = *(const bf16x8*)&Bs[1][boff + 3 * 16 * 32];
        mfma_grp(&Ah[1][0], aoff, b0, b1, b2, b3, acc);
        mfma_grp(&Al[1][0], aoff, b0, b1, b2, b3, acc);
      }
      __syncthreads();
    }
    float* Ob = out + (size_t)(t * 16 + b) * CN;
#pragma unroll
    for (int i = 0; i < 4; ++i) {
#pragma unroll
      for (int rg = 0; rg < 4; ++rg) {
        int c = mt * 128 + moff + i * 16 + quad * 4 + rg;
        float4 bn = *(const float4*)&bns[4 * (768 + c)];
        float hsc = 0.5f * bn.x;
        float hsh = 0.5f * bn.y;
        float rcp = bn.z;
        float* row2 = Ob + (size_t)c * N_ + nt * 128 + noff + r;
#pragma unroll
        for (int j = 0; j < 4; ++j) {
          float m = acc[i * 4 + j][rg] * hsc + hsh;
          int s = (m >= 1.0f);
          row2[j * 16] = s ? 1.0f : 0.0f;
          acc[i * 4 + j][rg] = s ? 0.f : m * rcp;
        }
      }
    }
  }
}

extern "C" void kernel_launch(void* const* d_in, const int* in_sizes, int n_in,
                              void* d_out, int out_size, void* d_ws, size_t ws_size,
                              hipStream_t stream) {
  const float* x   = (const float*)d_in[0];
  const float* qw  = (const float*)d_in[2];
  const float* qg  = (const float*)d_in[3];
  const float* qb  = (const float*)d_in[4];
  const float* qm  = (const float*)d_in[5];
  const float* qv  = (const float*)d_in[6];
  const float* kw  = (const float*)d_in[7];
  const float* kg  = (const float*)d_in[8];
  const float* kb  = (const float*)d_in[9];
  const float* km  = (const float*)d_in[10];
  const float* kvv = (const float*)d_in[11];
  const float* vw  = (const float*)d_in[12];
  const float* vg  = (const float*)d_in[13];
  const float* vb  = (const float*)d_in[14];
  const float* vm  = (const float*)d_in[15];
  const float* vv  = (const float*)d_in[16];
  const float* pw  = (const float*)d_in[17];
  const float* pb  = (const float*)d_in[18];
  const float* pg  = (const float*)d_in[19];
  const float* pbt = (const float*)d_in[20];
  const float* pm  = (const float*)d_in[21];
  const float* pv  = (const float*)d_in[22];

  float* out = (float*)d_out;
  float* vout = out + M_ELEMS;

  uint8_t* ws = (uint8_t*)d_ws;
  uint8_t* S   = ws + OFF_S;          /* SQ | SK | SV */
  ushort_t* Xc = (ushort_t*)(ws + OFF_XC);
  ushort_t* Sc = (ushort_t*)(ws + OFF_SC);
  float* KV    = (float*)(ws + OFF_KV);
  float* BNS   = (float*)(ws + OFF_BNS);
  ushort_t* Wc  = (ushort_t*)(ws + OFF_WC);
  ushort_t* Wpc = (ushort_t*)(ws + OFF_WPC);

  bn_prep<<<dim3(1), dim3(1024), 0, stream>>>(qg, qb, qm, qv, kg, kb, km, kvv,
                                              vg, vb, vm, vv, pb, pg, pbt, pm, pv, BNS);
  convert_w<<<dim3(1024), dim3(256), 0, stream>>>(qw, kw, vw, pw, Wc, Wpc);
  convert_x<<<dim3(2048), dim3(256), 0, stream>>>(x, Xc);
  gemm_qkv_lif<<<dim3(8, 6, 16), dim3(256), 0, stream>>>(Wc, Xc, BNS, S);
  kv_gram_tv<<<dim3(512), dim3(256), 0, stream>>>(S + 1ull * M_ELEMS, S + 2ull * M_ELEMS, KV, vout);
  attn_lif<<<dim3(2048), dim3(256), 0, stream>>>(S, KV, Sc);
  gemm_p_lif<<<dim3(8, 2, 16), dim3(256), 0, stream>>>(Wpc, Sc, BNS, out);
}